// Round 1
// baseline (543.105 us; speedup 1.0000x reference)
//
#include <hip/hip_runtime.h>
#include <math.h>

#define NB 16
#define LTOT 327
#define SDIM 256
#define ZD 64

// region starts (in l-space, l=0 is collapse token) and lengths
// cdr3:24 pep:16 mhc:48 hv:104 hj:16 lv:104 lj:14
__device__ __constant__ int d_starts[7] = {1, 25, 41, 89, 193, 209, 313};
__device__ __constant__ int d_lens[7]   = {24, 16, 48, 104, 16, 104, 14};

__device__ __forceinline__ int regid(int x) {
    return (x >= 1) + (x >= 25) + (x >= 41) + (x >= 89) + (x >= 193) + (x >= 209) + (x >= 313);
}

__device__ __forceinline__ int pair_id(int i, int j, int ri, int rj) {
    if ((i == 0) && (j == 0)) return 0;
    if ((i == 0) || (j == 0)) return 1;
    if ((ri == 1) && (rj == 1)) {
        int d = i > j ? i - j : j - i;
        if (d == 1) return 2;
        if (d != 0) return 3;
        return 0;                 // diagonal inside cdr3 stays 0 (matches jnp.where order)
    }
    if ((ri == 1) || (rj == 1)) return 4;
    if (ri == rj) return 5 + ri - 2;
    int a = (ri < rj ? ri : rj) - 2;
    int c = (ri < rj ? rj : ri) - 2;
    return 11 + a * (11 - a) / 2 + (c - a - 1);   // N_COND=6
}

// ---------------- s: (B, 327, 256) ----------------
__global__ __launch_bounds__(256) void s_kernel(
    const float* __restrict__ s0, const float* __restrict__ s1,
    const float* __restrict__ s2, const float* __restrict__ s3,
    const float* __restrict__ s4, const float* __restrict__ s5,
    const float* __restrict__ s6,
    const float* __restrict__ seqW, const float* __restrict__ seqb,
    const float* __restrict__ posW, const float* __restrict__ posb,
    const float* __restrict__ ctok, const float* __restrict__ cw,
    const float* __restrict__ rw,
    float* __restrict__ out)
{
    int blk = blockIdx.x;          // b*LTOT + l
    int l = blk % LTOT;
    int b = blk / LTOT;
    int e = threadIdx.x;

    if (l == 0) {
        out[(size_t)blk * SDIM + e] = cw[0] * ctok[e];
        return;
    }

    __shared__ float sh_seq[21];
    __shared__ float sh_pe[64];

    int k = (l >= 25) + (l >= 41) + (l >= 89) + (l >= 193) + (l >= 209) + (l >= 313);
    int pl = l - d_starts[k];

    const float* sp;
    switch (k) {
        case 0: sp = s0; break; case 1: sp = s1; break; case 2: sp = s2; break;
        case 3: sp = s3; break; case 4: sp = s4; break; case 5: sp = s5; break;
        default: sp = s6;
    }
    if (e < 21) sh_seq[e] = sp[((size_t)b * d_lens[k] + pl) * 21 + e];
    if (e < 64) {
        // 10000^(e/64) via exp2; log2(10000) = 13.287712379549449
        float scale = exp2f(-(float)e * (13.287712379549449f / 64.0f));
        float ang = (float)pl * scale;
        sh_pe[e] = (e & 1) ? cosf(ang) : sinf(ang);
    }
    __syncthreads();

    float se = seqb[e];
    const float* wrow = seqW + e * 21;
    #pragma unroll
    for (int d = 0; d < 21; d++) se = fmaf(sh_seq[d], wrow[d], se);

    float pe = posb[e];
    const float* pwrow = posW + e * 64;
    #pragma unroll 8
    for (int i2 = 0; i2 < 64; i2++) pe = fmaf(sh_pe[i2], pwrow[i2], pe);

    float w0 = rw[2 * k], w1 = rw[2 * k + 1];
    out[(size_t)blk * SDIM + e] = w0 * se + w1 * pe;
}

// ---------------- z: (B, 327, 327, 64) ----------------
#define TSTRIDE 68   // 64 + 4 pad: spreads LDS banks across p rows, keeps 16B alignment

__global__ __launch_bounds__(256) void z_kernel(
    const float* __restrict__ p1W, const float* __restrict__ p1b,
    const float* __restrict__ p2W, const float* __restrict__ p2b,
    float* __restrict__ outz)
{
    __shared__ __align__(16) float table[32 * TSTRIDE];
    __shared__ int pr[LTOT];

    int t = threadIdx.x;

    // build the 32-row lookup table: row[p] = [p1W[:,p/4]+p1b | p2W[:,p%4]+p2b]
    for (int idx = t; idx < 32 * 64; idx += 256) {
        int p = idx >> 6, c = idx & 63;
        float v;
        if (c < 32) v = p1W[c * 8 + (p >> 2)] + p1b[c];
        else        v = p2W[(c - 32) * 4 + (p & 3)] + p2b[c - 32];
        table[p * TSTRIDE + c] = v;
    }

    int blk = blockIdx.x;          // b*LTOT + i
    int i = blk % LTOT;
    int ri = regid(i);
    for (int j = t; j < LTOT; j += 256) pr[j] = pair_id(i, j, ri, regid(j));
    __syncthreads();

    float4* dst = (float4*)(outz + (size_t)blk * (LTOT * ZD));
    const int NF4 = LTOT * (ZD / 4);   // 5232 float4 per (b,i) row
    for (int idx = t; idx < NF4; idx += 256) {
        int j = idx >> 4, c4 = idx & 15;
        const float4* src = (const float4*)(table + pr[j] * TSTRIDE + c4 * 4);
        dst[idx] = *src;
    }
}

extern "C" void kernel_launch(void* const* d_in, const int* in_sizes, int n_in,
                              void* d_out, int out_size, void* d_ws, size_t ws_size,
                              hipStream_t stream) {
    const float* seq0 = (const float*)d_in[0];   // cdr3_xt (16,24,21)
    const float* seq1 = (const float*)d_in[1];   // pep    (16,16,21)
    const float* seq2 = (const float*)d_in[2];   // mhc    (16,48,21)
    const float* seq3 = (const float*)d_in[3];   // hv     (16,104,21)
    const float* seq4 = (const float*)d_in[4];   // hj     (16,16,21)
    const float* seq5 = (const float*)d_in[5];   // lv     (16,104,21)
    const float* seq6 = (const float*)d_in[6];   // lj     (16,14,21)
    const float* seqW = (const float*)d_in[7];   // (256,21)
    const float* seqb = (const float*)d_in[8];   // (256)
    const float* posW = (const float*)d_in[9];   // (256,64)
    const float* posb = (const float*)d_in[10];  // (256)
    const float* p1W  = (const float*)d_in[11];  // (32,8)
    const float* p1b  = (const float*)d_in[12];  // (32)
    const float* p2W  = (const float*)d_in[13];  // (32,4)
    const float* p2b  = (const float*)d_in[14];  // (32)
    const float* ctok = (const float*)d_in[15];  // (1,256)
    const float* cw   = (const float*)d_in[16];  // (1)
    const float* rw   = (const float*)d_in[17];  // (7,2)
    // d_in[18..24] = masks (unused by reference)

    float* out = (float*)d_out;
    float* outz = out + (size_t)NB * LTOT * SDIM;   // z follows s in flat output

    s_kernel<<<NB * LTOT, 256, 0, stream>>>(seq0, seq1, seq2, seq3, seq4, seq5, seq6,
                                            seqW, seqb, posW, posb, ctok, cw, rw, out);
    z_kernel<<<NB * LTOT, 256, 0, stream>>>(p1W, p1b, p2W, p2b, outz);
}

// Round 2
// 509.726 us; speedup vs baseline: 1.0655x; 1.0655x over previous
//
#include <hip/hip_runtime.h>
#include <math.h>

#define NB 16
#define LTOT 327
#define SDIM 256
#define ZD 64

// region starts (l-space; l=0 collapse token) and lengths
__device__ __constant__ int d_starts[7] = {1, 25, 41, 89, 193, 209, 313};
__device__ __constant__ int d_lens[7]   = {24, 16, 48, 104, 16, 104, 14};

// j-segment boundaries: [token][cdr3][pep][mhc][hv][hj][lv][lj]
__device__ __constant__ int seg_s[8] = {0, 1, 25, 41, 89, 193, 209, 313};
__device__ __constant__ int seg_e[8] = {1, 25, 41, 89, 193, 209, 313, 327};

__device__ __forceinline__ int regid(int x) {
    return (x >= 1) + (x >= 25) + (x >= 41) + (x >= 89) + (x >= 193) + (x >= 209) + (x >= 313);
}

__device__ __forceinline__ int pair_id(int i, int j, int ri, int rj) {
    if ((i == 0) && (j == 0)) return 0;
    if ((i == 0) || (j == 0)) return 1;
    if ((ri == 1) && (rj == 1)) {
        int d = i > j ? i - j : j - i;
        if (d == 1) return 2;
        if (d != 0) return 3;
        return 0;                 // cdr3 diagonal stays 0 (matches jnp.where order)
    }
    if ((ri == 1) || (rj == 1)) return 4;
    if (ri == rj) return 5 + ri - 2;
    int a = (ri < rj ? ri : rj) - 2;
    int c = (ri < rj ? rj : ri) - 2;
    return 11 + a * (11 - a) / 2 + (c - a - 1);   // N_COND=6
}

// -------- pe: (327, 256)  b-invariant positional part, pre-scaled by region_w[k][1]
__global__ __launch_bounds__(256) void pe_kernel(
    const float* __restrict__ posW, const float* __restrict__ posb,
    const float* __restrict__ rw, float* __restrict__ pe_full)
{
    int l = blockIdx.x;            // 0..326; l=0 unused downstream
    int e = threadIdx.x;
    __shared__ float sh_pe[64];

    int k = (l >= 25) + (l >= 41) + (l >= 89) + (l >= 193) + (l >= 209) + (l >= 313);
    int pl = (l == 0) ? 0 : (l - d_starts[k]);
    if (e < 64) {
        float scale = exp2f(-(float)e * (13.287712379549449f / 64.0f)); // 10000^(-e/64)
        float ang = (float)pl * scale;
        sh_pe[e] = (e & 1) ? cosf(ang) : sinf(ang);
    }
    __syncthreads();

    float pe = posb[e];
    const float* pwrow = posW + e * 64;
    #pragma unroll 8
    for (int i2 = 0; i2 < 64; i2++) pe = fmaf(sh_pe[i2], pwrow[i2], pe);
    pe_full[(size_t)l * SDIM + e] = rw[2 * k + 1] * pe;
}

// -------- s: (B, 327, 256)
__global__ __launch_bounds__(256) void s_kernel2(
    const float* __restrict__ s0, const float* __restrict__ s1,
    const float* __restrict__ s2, const float* __restrict__ s3,
    const float* __restrict__ s4, const float* __restrict__ s5,
    const float* __restrict__ s6,
    const float* __restrict__ seqW, const float* __restrict__ seqb,
    const float* __restrict__ ctok, const float* __restrict__ cw,
    const float* __restrict__ rw, const float* __restrict__ pe_full,
    float* __restrict__ out)
{
    int blk = blockIdx.x;          // b*LTOT + l
    int l = blk % LTOT;
    int b = blk / LTOT;
    int e = threadIdx.x;

    if (l == 0) {
        out[(size_t)blk * SDIM + e] = cw[0] * ctok[e];
        return;
    }
    __shared__ float sh_seq[21];
    int k = (l >= 25) + (l >= 41) + (l >= 89) + (l >= 193) + (l >= 209) + (l >= 313);
    int pl = l - d_starts[k];
    const float* sp;
    switch (k) {
        case 0: sp = s0; break; case 1: sp = s1; break; case 2: sp = s2; break;
        case 3: sp = s3; break; case 4: sp = s4; break; case 5: sp = s5; break;
        default: sp = s6;
    }
    if (e < 21) sh_seq[e] = sp[((size_t)b * d_lens[k] + pl) * 21 + e];
    __syncthreads();

    float se = seqb[e];
    const float* wrow = seqW + e * 21;
    #pragma unroll
    for (int d = 0; d < 21; d++) se = fmaf(sh_seq[d], wrow[d], se);

    out[(size_t)blk * SDIM + e] = rw[2 * k] * se + pe_full[(size_t)l * SDIM + e];
}

// -------- fallback single-pass s (if ws too small) --------
__global__ __launch_bounds__(256) void s_kernel(
    const float* __restrict__ s0, const float* __restrict__ s1,
    const float* __restrict__ s2, const float* __restrict__ s3,
    const float* __restrict__ s4, const float* __restrict__ s5,
    const float* __restrict__ s6,
    const float* __restrict__ seqW, const float* __restrict__ seqb,
    const float* __restrict__ posW, const float* __restrict__ posb,
    const float* __restrict__ ctok, const float* __restrict__ cw,
    const float* __restrict__ rw,
    float* __restrict__ out)
{
    int blk = blockIdx.x;
    int l = blk % LTOT;
    int b = blk / LTOT;
    int e = threadIdx.x;
    if (l == 0) { out[(size_t)blk * SDIM + e] = cw[0] * ctok[e]; return; }
    __shared__ float sh_seq[21];
    __shared__ float sh_pe[64];
    int k = (l >= 25) + (l >= 41) + (l >= 89) + (l >= 193) + (l >= 209) + (l >= 313);
    int pl = l - d_starts[k];
    const float* sp;
    switch (k) {
        case 0: sp = s0; break; case 1: sp = s1; break; case 2: sp = s2; break;
        case 3: sp = s3; break; case 4: sp = s4; break; case 5: sp = s5; break;
        default: sp = s6;
    }
    if (e < 21) sh_seq[e] = sp[((size_t)b * d_lens[k] + pl) * 21 + e];
    if (e < 64) {
        float scale = exp2f(-(float)e * (13.287712379549449f / 64.0f));
        float ang = (float)pl * scale;
        sh_pe[e] = (e & 1) ? cosf(ang) : sinf(ang);
    }
    __syncthreads();
    float se = seqb[e];
    const float* wrow = seqW + e * 21;
    #pragma unroll
    for (int d = 0; d < 21; d++) se = fmaf(sh_seq[d], wrow[d], se);
    float pe = posb[e];
    const float* pwrow = posW + e * 64;
    #pragma unroll 8
    for (int i2 = 0; i2 < 64; i2++) pe = fmaf(sh_pe[i2], pwrow[i2], pe);
    out[(size_t)blk * SDIM + e] = rw[2 * k] * se + rw[2 * k + 1] * pe;
}

// -------- z: (B, 327, 327, 64) — segment-hoisted pure-streaming stores --------
#define TSTRIDE 68   // 64 + 4 pad, keeps 16B alignment

__global__ __launch_bounds__(256) void z_kernel(
    const float* __restrict__ p1W, const float* __restrict__ p1b,
    const float* __restrict__ p2W, const float* __restrict__ p2b,
    float* __restrict__ outz)
{
    __shared__ __align__(16) float table[32 * TSTRIDE];
    int t = threadIdx.x;

    // 32-row lookup table: row[p] = [p1W[:,p/4]+p1b | p2W[:,p%4]+p2b]
    for (int idx = t; idx < 32 * 64; idx += 256) {
        int p = idx >> 6, c = idx & 63;
        float v;
        if (c < 32) v = p1W[c * 8 + (p >> 2)] + p1b[c];
        else        v = p2W[(c - 32) * 4 + (p & 3)] + p2b[c - 32];
        table[p * TSTRIDE + c] = v;
    }
    __syncthreads();

    int blk = blockIdx.x;          // b*LTOT + i
    int i = blk % LTOT;
    int ri = regid(i);
    int c4 = t & 15;               // which float4 of the 16 in a 64-float row
    int jo = t >> 4;               // j offset within a 16-row stripe

    float4* dst = (float4*)(outz + (size_t)blk * (LTOT * ZD));

    #pragma unroll
    for (int s = 0; s < 8; s++) {
        int js = seg_s[s], je = seg_e[s];
        if (ri == 1 && s == 1) {
            // cdr3 row × cdr3 segment: p varies with |i-j| in {0(diag),2(adj),3}
            float4 v0 = *(const float4*)(table + 0 * TSTRIDE + c4 * 4);
            float4 v2 = *(const float4*)(table + 2 * TSTRIDE + c4 * 4);
            float4 v3 = *(const float4*)(table + 3 * TSTRIDE + c4 * 4);
            for (int j = js + jo; j < je; j += 16) {
                int d = i > j ? i - j : j - i;
                float4 v = (d == 0) ? v0 : ((d == 1) ? v2 : v3);
                dst[j * 16 + c4] = v;
            }
        } else {
            int p = pair_id(i, js, ri, regid(js));   // uniform over the segment
            float4 v = *(const float4*)(table + p * TSTRIDE + c4 * 4);
            for (int j = js + jo; j < je; j += 16) {
                dst[j * 16 + c4] = v;                // pure streaming store
            }
        }
    }
}

extern "C" void kernel_launch(void* const* d_in, const int* in_sizes, int n_in,
                              void* d_out, int out_size, void* d_ws, size_t ws_size,
                              hipStream_t stream) {
    const float* seq0 = (const float*)d_in[0];
    const float* seq1 = (const float*)d_in[1];
    const float* seq2 = (const float*)d_in[2];
    const float* seq3 = (const float*)d_in[3];
    const float* seq4 = (const float*)d_in[4];
    const float* seq5 = (const float*)d_in[5];
    const float* seq6 = (const float*)d_in[6];
    const float* seqW = (const float*)d_in[7];
    const float* seqb = (const float*)d_in[8];
    const float* posW = (const float*)d_in[9];
    const float* posb = (const float*)d_in[10];
    const float* p1W  = (const float*)d_in[11];
    const float* p1b  = (const float*)d_in[12];
    const float* p2W  = (const float*)d_in[13];
    const float* p2b  = (const float*)d_in[14];
    const float* ctok = (const float*)d_in[15];
    const float* cw   = (const float*)d_in[16];
    const float* rw   = (const float*)d_in[17];

    float* out = (float*)d_out;
    float* outz = out + (size_t)NB * LTOT * SDIM;

    // z first: it's the big one; let it own the machine immediately
    z_kernel<<<NB * LTOT, 256, 0, stream>>>(p1W, p1b, p2W, p2b, outz);

    if (ws_size >= (size_t)LTOT * SDIM * sizeof(float)) {
        float* pe_full = (float*)d_ws;
        pe_kernel<<<LTOT, 256, 0, stream>>>(posW, posb, rw, pe_full);
        s_kernel2<<<NB * LTOT, 256, 0, stream>>>(seq0, seq1, seq2, seq3, seq4, seq5, seq6,
                                                 seqW, seqb, ctok, cw, rw, pe_full, out);
    } else {
        s_kernel<<<NB * LTOT, 256, 0, stream>>>(seq0, seq1, seq2, seq3, seq4, seq5, seq6,
                                                seqW, seqb, posW, posb, ctok, cw, rw, out);
    }
}